// Round 7
// baseline (1380.865 us; speedup 1.0000x reference)
//
#include <hip/hip_runtime.h>
#include <hip/hip_bf16.h>

// SelfAttention B=4,S=2048,D=512,H=8 — bf16-MFMA, fp32 softmax.
// R7: attn bh-clustered XCD mapping (one bh's K/V per XCD L2);
//     k_gemm_out split-K=4 + reduce (partials in dead Qc buffer).

using bf16x8 = __attribute__((ext_vector_type(8))) short;
using f32x4  = __attribute__((ext_vector_type(4))) float;
typedef unsigned short u16;

__device__ __forceinline__ u16 f2bf(float f) {
  union { float f; unsigned u; } c; c.f = f;
  unsigned r = c.u + 0x7fffu + ((c.u >> 16) & 1u);  // RNE
  return (u16)(r >> 16);
}

__device__ __forceinline__ void gload16(const void* g, void* l) {
  __builtin_amdgcn_global_load_lds((const __attribute__((address_space(1))) unsigned int*)g,
                                   (__attribute__((address_space(3))) unsigned int*)l, 16, 0, 0);
}

__global__ void k_cvt(const float* __restrict__ s, u16* __restrict__ d, int n4) {
  int i = blockIdx.x * 256 + threadIdx.x;
  if (i >= n4) return;
  float4 v = reinterpret_cast<const float4*>(s)[i];
  ushort4 o;
  o.x = f2bf(v.x); o.y = f2bf(v.y); o.z = f2bf(v.z); o.w = f2bf(v.w);
  reinterpret_cast<ushort4*>(d)[i] = o;
}

// ---------------- QKV projection GEMM (NT): out = xb @ W[t*8+h]^T ------------
__global__ __launch_bounds__(256) void k_gemm_qkv(
    const u16* __restrict__ xb, const u16* __restrict__ w,
    u16* __restrict__ Qc, u16* __restrict__ Kc, u16* __restrict__ VTc,
    int h0, int HC)
{
  __shared__ u16 As[128][32];
  __shared__ u16 Bs[128][32];

  const int m0 = blockIdx.x * 128;
  const int n0 = blockIdx.y * 128;
  const int zz = blockIdx.z;
  const int t  = zz / HC, hr = zz % HC;
  const int h  = h0 + hr;

  const int tid  = threadIdx.x;
  const int lane = tid & 63, wv = tid >> 6;
  const int wr = (wv >> 1) * 64, wc = (wv & 1) * 64;
  const int r16 = lane & 15, kg = lane >> 4;

  const u16* wbase = w + (size_t)(t * 8 + h) * 512 * 512;
  const int strow = tid >> 2;
  const int sc4   = (tid & 3) * 8;

  const u16* gaa = xb    + (size_t)(m0 + strow) * 512 + sc4;
  const u16* gbb = wbase + (size_t)(n0 + strow) * 512 + sc4;
  char* AsB = (char*)&As[0][0] + wv * 1024;
  char* BsB = (char*)&Bs[0][0] + wv * 1024;

  f32x4 acc[4][4];
  f32x4 zero = {0.f, 0.f, 0.f, 0.f};
#pragma unroll
  for (int i = 0; i < 4; ++i)
#pragma unroll
    for (int j = 0; j < 4; ++j) acc[i][j] = zero;

  for (int kt = 0; kt < 16; ++kt) {
    __syncthreads();
    const int ko = kt * 32;
    gload16(gaa + ko,            AsB);
    gload16(gaa + 64 * 512 + ko, AsB + 4096);
    gload16(gbb + ko,            BsB);
    gload16(gbb + 64 * 512 + ko, BsB + 4096);
    __syncthreads();
    bf16x8 af[4], bfv[4];
#pragma unroll
    for (int i = 0; i < 4; ++i) af[i]  = *(const bf16x8*)&As[wr + i * 16 + r16][kg * 8];
#pragma unroll
    for (int j = 0; j < 4; ++j) bfv[j] = *(const bf16x8*)&Bs[wc + j * 16 + r16][kg * 8];
#pragma unroll
    for (int i = 0; i < 4; ++i)
#pragma unroll
      for (int j = 0; j < 4; ++j)
        acc[i][j] = __builtin_amdgcn_mfma_f32_16x16x32_bf16(af[i], bfv[j], acc[i][j], 0, 0, 0);
  }

  // C lane map: row=(lane>>4)*4+reg, col=lane&15
#pragma unroll
  for (int i = 0; i < 4; ++i) {
    const int mbase = m0 + wr + i * 16 + kg * 4;
    const int b   = mbase >> 11;
    const int sl  = mbase & 2047;
    const int bhc = b * HC + hr;
#pragma unroll
    for (int j = 0; j < 4; ++j) {
      const int col = n0 + wc + j * 16 + r16;
      if (t == 2) {        // V transposed: VT[bhc][e=col][s]
        ushort4 o;
        o.x = f2bf(acc[i][j][0]); o.y = f2bf(acc[i][j][1]);
        o.z = f2bf(acc[i][j][2]); o.w = f2bf(acc[i][j][3]);
        *(ushort4*)&VTc[((size_t)bhc * 512 + col) * 2048 + sl] = o;
      } else if (t == 1) { // K: swizzled chunk image for k_attn
#pragma unroll
        for (int q = 0; q < 4; ++q) {
          const int s   = sl + q;
          const int row = s & 63;
          const size_t idx = ((size_t)bhc << 20)
                           + (size_t)((s >> 6) * 4 + (col >> 7)) * 8192
                           + row * 128 + ((col & 127) ^ ((row & 7) << 3));
          Kc[idx] = f2bf(acc[i][j][q]);
        }
      } else {             // Q: plain row-major [bhc][s][e]
#pragma unroll
        for (int q = 0; q < 4; ++q)
          Qc[((size_t)bhc * 2048 + sl + q) * 512 + col] = f2bf(acc[i][j][q]);
      }
    }
  }
}

// ---------------- flash attention v4 ----------------
// grid (64, 4*HC), bh-clustered XCD mapping: XCD x owns bhc {x*HC/2 ..},
// qt sequential -> one bh's K/V (~4MB) resident in that XCD's L2.
__global__ __launch_bounds__(256) void k_attn(
    const u16* __restrict__ Qc, const u16* __restrict__ Kc, const u16* __restrict__ VTc,
    const int* __restrict__ mask, u16* __restrict__ catc, int HC)
{
  __shared__ u16  Qs[32 * 512];      // XOR-swizzled rows (32 KB)
  __shared__ u16  Ks[2 * 8192];      // 2 chunk buffers [64][128] swizzled (32 KB)
  __shared__ float S_lds[32][68];
  __shared__ u16  P_lds[32][72];
  __shared__ float m_run[32], l_run[32], alpha_s[32];

  const int lin = blockIdx.x + (blockIdx.y << 6);
  int qt, bhc;
  if (HC >= 2) {           // bh-clustered: xcd = lin&7 (hw round-robin)
    const int pxb  = HC >> 1;         // bh per XCD
    const int slot = lin >> 3;        // 0 .. 32*HC-1
    bhc = (lin & 7) * pxb + (slot >> 6);
    qt  = slot & 63;
  } else {
    qt = lin & 63; bhc = lin >> 6;
  }

  const int b = bhc / HC, hr = bhc % HC;
  const int q0 = qt * 32;

  const int tid = threadIdx.x, lane = tid & 63, wv = tid >> 6;
  const int r16 = lane & 15, kg = lane >> 4;

  const u16* Qg = Qc + ((size_t)bhc * 2048 + q0) * 512;
  const u16* Kg = Kc + ((size_t)bhc << 20);
  const u16* Vg = VTc + (size_t)bhc * 512 * 2048;
  const int* mrow = mask + b * 2048;

  // stage Q swizzled
  for (int s = tid; s < 2048; s += 256) {
    const int row = s >> 6, col = (s & 63) * 8;
    *(int4*)&Qs[row * 512 + (col ^ ((row & 7) << 3))] =
        *(const int4*)(Qg + row * 512 + col);
  }
  if (tid < 32) { m_run[tid] = -__builtin_inff(); l_run[tid] = 0.f; }

  // K chunk issue: wave wv loads exactly rows 16wv..16wv+15 (the rows it reads)
  auto kissue = [&](int gi, int cur) {
    const u16* g = Kg + (size_t)gi * 8192 + wv * 2048 + lane * 8;
    u16* l = &Ks[cur * 8192 + wv * 2048];
#pragma unroll
    for (int r = 0; r < 4; ++r)
      gload16(g + r * 512, l + r * 512);
  };

  kissue(0, 0);
  kissue(1, 1);

  asm volatile("s_waitcnt lgkmcnt(0)" ::: "memory");
  __builtin_amdgcn_s_barrier();    // Q visible; K gloads stay in flight

  const int sm_row = tid >> 3, sm_c0 = (tid & 7) * 8;
  const int rm = mrow[q0 + sm_row];
  const int krow = wv * 16 + r16;
  const int kswz = (krow & 7) << 3;

  f32x4 acc[2][8];
  f32x4 zero = {0.f, 0.f, 0.f, 0.f};
#pragma unroll
  for (int mi = 0; mi < 2; ++mi)
#pragma unroll
    for (int nf = 0; nf < 8; ++nf) acc[mi][nf] = zero;

  const float scale = 0.044194173824159216f;  // 1/sqrt(512)

  for (int it = 0; it < 32; ++it) {
    const int t0 = it * 64;
    f32x4 sacc[2] = {zero, zero};

    // ---- QK^T over 4 d-chunks; barrier-free 2-deep K pipeline ----
#pragma unroll
    for (int c = 0; c < 4; ++c) {
      const int gi = it * 4 + c;
      const int cur = gi & 1;
      asm volatile("s_waitcnt vmcnt(4)" ::: "memory");  // chunk gi landed
      __builtin_amdgcn_s_setprio(1);
#pragma unroll
      for (int ks = 0; ks < 4; ++ks) {
        bf16x8 kb = *(const bf16x8*)&Ks[cur * 8192 + krow * 128 + ((ks * 32 + kg * 8) ^ kswz)];
#pragma unroll
        for (int mi = 0; mi < 2; ++mi) {
          const int qrow = mi * 16 + r16;
          bf16x8 qa = *(const bf16x8*)&Qs[qrow * 512 +
              ((c * 128 + ks * 32 + kg * 8) ^ ((qrow & 7) << 3))];
          sacc[mi] = __builtin_amdgcn_mfma_f32_16x16x32_bf16(qa, kb, sacc[mi], 0, 0, 0);
        }
      }
      __builtin_amdgcn_s_setprio(0);
      if (c == 3) {  // publish raw S strip
#pragma unroll
        for (int mi = 0; mi < 2; ++mi)
#pragma unroll
          for (int q = 0; q < 4; ++q)
            S_lds[mi * 16 + kg * 4 + q][wv * 16 + r16] = sacc[mi][q];
      }
      asm volatile("s_waitcnt lgkmcnt(0)" ::: "memory");  // my ds ops done
      __builtin_amdgcn_sched_barrier(0);
      if (gi + 2 < 128) kissue(gi + 2, cur);              // wave-private rows
    }
    __builtin_amdgcn_s_barrier();    // S visible; K loads in flight

    // ---- V fragment preload (independent of softmax) ----
    bf16x8 vfrag[2][8];
#pragma unroll
    for (int ks = 0; ks < 2; ++ks)
#pragma unroll
      for (int nf = 0; nf < 8; ++nf)
        vfrag[ks][nf] = *(const bf16x8*)(Vg +
            (size_t)(wv * 128 + nf * 16 + r16) * 2048 + t0 + ks * 32 + kg * 8);

    // ---- online softmax (32 rows x 64 cols, 8 threads/row) ----
    {
      float4 sA = *(float4*)&S_lds[sm_row][sm_c0];
      float4 sB = *(float4*)&S_lds[sm_row][sm_c0 + 4];
      const int4 cA = *(const int4*)(mrow + t0 + sm_c0);
      const int4 cB = *(const int4*)(mrow + t0 + sm_c0 + 4);
      float s0 = (rm && cA.x) ? sA.x * scale : -1e9f;
      float s1 = (rm && cA.y) ? sA.y * scale : -1e9f;
      float s2 = (rm && cA.z) ? sA.z * scale : -1e9f;
      float s3 = (rm && cA.w) ? sA.w * scale : -1e9f;
      float s4 = (rm && cB.x) ? sB.x * scale : -1e9f;
      float s5 = (rm && cB.y) ? sB.y * scale : -1e9f;
      float s6 = (rm && cB.z) ? sB.z * scale : -1e9f;
      float s7 = (rm && cB.w) ? sB.w * scale : -1e9f;
      float mt = fmaxf(fmaxf(fmaxf(s0, s1), fmaxf(s2, s3)),
                       fmaxf(fmaxf(s4, s5), fmaxf(s6, s7)));
      mt = fmaxf(mt, __shfl_xor(mt, 1));
      mt = fmaxf(mt, __shfl_xor(mt, 2));
      mt = fmaxf(mt, __shfl_xor(mt, 4));
      const float mo = m_run[sm_row];
      const float mn = fmaxf(mo, mt);
      const float al = __expf(mo - mn);
      float p0 = __expf(s0 - mn), p1 = __expf(s1 - mn);
      float p2 = __expf(s2 - mn), p3 = __expf(s3 - mn);
      float p4 = __expf(s4 - mn), p5 = __expf(s5 - mn);
      float p6 = __expf(s6 - mn), p7 = __expf(s7 - mn);
      float ps = ((p0 + p1) + (p2 + p3)) + ((p4 + p5) + (p6 + p7));
      ps += __shfl_xor(ps, 1); ps += __shfl_xor(ps, 2); ps += __shfl_xor(ps, 4);
      ushort4 w0, w1;
      w0.x = f2bf(p0); w0.y = f2bf(p1); w0.z = f2bf(p2); w0.w = f2bf(p3);
      w1.x = f2bf(p4); w1.y = f2bf(p5); w1.z = f2bf(p6); w1.w = f2bf(p7);
      *(ushort4*)&P_lds[sm_row][sm_c0]     = w0;
      *(ushort4*)&P_lds[sm_row][sm_c0 + 4] = w1;
      if ((tid & 7) == 0) {
        m_run[sm_row] = mn;
        l_run[sm_row] = l_run[sm_row] * al + ps;
        alpha_s[sm_row] = al;
      }
    }
    asm volatile("s_waitcnt lgkmcnt(0)" ::: "memory");
    __builtin_amdgcn_s_barrier();    // P/alpha visible

    // ---- rescale + PV ----
    float alq[2][4];
#pragma unroll
    for (int mi = 0; mi < 2; ++mi)
#pragma unroll
      for (int q = 0; q < 4; ++q) alq[mi][q] = alpha_s[mi * 16 + kg * 4 + q];
#pragma unroll
    for (int mi = 0; mi < 2; ++mi)
#pragma unroll
      for (int nf = 0; nf < 8; ++nf) {
        acc[mi][nf][0] *= alq[mi][0]; acc[mi][nf][1] *= alq[mi][1];
        acc[mi][nf][2] *= alq[mi][2]; acc[mi][nf][3] *= alq[mi][3];
      }
    __builtin_amdgcn_s_setprio(1);
#pragma unroll
    for (int ks = 0; ks < 2; ++ks) {
      bf16x8 pa0 = *(const bf16x8*)&P_lds[r16][ks * 32 + kg * 8];
      bf16x8 pa1 = *(const bf16x8*)&P_lds[16 + r16][ks * 32 + kg * 8];
#pragma unroll
      for (int nf = 0; nf < 8; ++nf) {
        acc[0][nf] = __builtin_amdgcn_mfma_f32_16x16x32_bf16(pa0, vfrag[ks][nf], acc[0][nf], 0, 0, 0);
        acc[1][nf] = __builtin_amdgcn_mfma_f32_16x16x32_bf16(pa1, vfrag[ks][nf], acc[1][nf], 0, 0, 0);
      }
    }
    __builtin_amdgcn_s_setprio(0);
  }

  // ---- epilogue ----
  float rinv[2][4];
#pragma unroll
  for (int mi = 0; mi < 2; ++mi)
#pragma unroll
    for (int q = 0; q < 4; ++q) rinv[mi][q] = 1.0f / l_run[mi * 16 + kg * 4 + q];
  const int ldc = HC * 512;
#pragma unroll
  for (int mi = 0; mi < 2; ++mi)
#pragma unroll
    for (int nf = 0; nf < 8; ++nf) {
      const int col = hr * 512 + wv * 128 + nf * 16 + r16;
#pragma unroll
      for (int q = 0; q < 4; ++q) {
        const int row = b * 2048 + q0 + mi * 16 + kg * 4 + q;
        catc[(size_t)row * ldc + col] = f2bf(acc[mi][nf][q] * rinv[mi][q]);
      }
    }
}

// ------------- output projection, split-K=4 (HC=8 path): partial[z] = cat_z @ Wp_z^T
__global__ __launch_bounds__(256) void k_gemm_out_sk(
    const u16* __restrict__ A, const u16* __restrict__ Bw, float* __restrict__ partial)
{
  __shared__ u16 As[128][32];
  __shared__ u16 Bs[128][32];

  const int m0 = blockIdx.x * 128;
  const int n0 = blockIdx.y * 128;
  const int z  = blockIdx.z;          // k-chunk: cols [z*1024, z*1024+1024)
  const int tid = threadIdx.x, lane = tid & 63, wv = tid >> 6;
  const int wr = (wv >> 1) * 64, wc = (wv & 1) * 64;
  const int r16 = lane & 15, kg = lane >> 4;
  const int strow = tid >> 2, sc4 = (tid & 3) * 8;

  const u16* gaa = A  + (size_t)(m0 + strow) * 4096 + z * 1024 + sc4;
  const u16* gbb = Bw + (size_t)(n0 + strow) * 4096 + z * 1024 + sc4;
  char* AsB = (char*)&As[0][0] + wv * 1024;
  char* BsB = (char*)&Bs[0][0] + wv * 1024;

  f32x4 acc[4][4];
  f32x4 zero = {0.f, 0.f, 0.f, 0.f};
#pragma unroll
  for (int i = 0; i < 4; ++i)
#pragma unroll
    for (int j = 0; j < 4; ++j) acc[i][j] = zero;

  for (int kt = 0; kt < 32; ++kt) {
    __syncthreads();
    const int ko = kt * 32;
    gload16(gaa + ko,                     AsB);
    gload16(gaa + (size_t)64 * 4096 + ko, AsB + 4096);
    gload16(gbb + ko,                     BsB);
    gload16(gbb + (size_t)64 * 4096 + ko, BsB + 4096);
    __syncthreads();
    bf16x8 af[4], bfv[4];
#pragma unroll
    for (int i = 0; i < 4; ++i) af[i]  = *(const bf16x8*)&As[wr + i * 16 + r16][kg * 8];
#pragma unroll
    for (int j = 0; j < 4; ++j) bfv[j] = *(const bf16x8*)&Bs[wc + j * 16 + r16][kg * 8];
#pragma unroll
    for (int i = 0; i < 4; ++i)
#pragma unroll
      for (int j = 0; j < 4; ++j)
        acc[i][j] = __builtin_amdgcn_mfma_f32_16x16x32_bf16(af[i], bfv[j], acc[i][j], 0, 0, 0);
  }

  float* dst = partial + (size_t)z * 4194304;
#pragma unroll
  for (int i = 0; i < 4; ++i)
#pragma unroll
    for (int j = 0; j < 4; ++j) {
      const int col = n0 + wc + j * 16 + r16;
#pragma unroll
      for (int q = 0; q < 4; ++q) {
        const int row = m0 + wr + i * 16 + kg * 4 + q;
        dst[(size_t)row * 512 + col] = acc[i][j][q];
      }
    }
}

__global__ void k_red4(const float* __restrict__ p, float* __restrict__ out, int n4) {
  int i = blockIdx.x * 256 + threadIdx.x;
  if (i >= n4) return;
  float4 a = reinterpret_cast<const float4*>(p)[i];
  float4 b = reinterpret_cast<const float4*>(p + 4194304)[i];
  float4 c = reinterpret_cast<const float4*>(p + 8388608)[i];
  float4 d = reinterpret_cast<const float4*>(p + 12582912)[i];
  float4 o;
  o.x = (a.x + b.x) + (c.x + d.x);
  o.y = (a.y + b.y) + (c.y + d.y);
  o.z = (a.z + b.z) + (c.z + d.z);
  o.w = (a.w + b.w) + (c.w + d.w);
  reinterpret_cast<float4*>(out)[i] = o;
}

// ------------- output projection GEMM (NT, accumulating) — HC<8 fallback
__global__ __launch_bounds__(256) void k_gemm_out(
    const u16* __restrict__ A, const u16* __restrict__ Bw, float* __restrict__ out,
    int HC, int h0, int init)
{
  __shared__ u16 As[128][32];
  __shared__ u16 Bs[128][32];

  const int m0 = blockIdx.x * 128;
  const int n0 = blockIdx.y * 128;
  const int tid = threadIdx.x, lane = tid & 63, wv = tid >> 6;
  const int wr = (wv >> 1) * 64, wc = (wv & 1) * 64;
  const int r16 = lane & 15, kg = lane >> 4;
  const int strow = tid >> 2, sc4 = (tid & 3) * 8;
  const size_t lda = (size_t)HC * 512;
  const int nkt = HC * 16;

  const u16* gaa = A  + (size_t)(m0 + strow) * lda + sc4;
  const u16* gbb = Bw + (size_t)(n0 + strow) * 4096 + h0 * 512 + sc4;
  char* AsB = (char*)&As[0][0] + wv * 1024;
  char* BsB = (char*)&Bs[0][0] + wv * 1024;

  f32x4 acc[4][4];
  f32x4 zero = {0.f, 0.f, 0.f, 0.f};
#pragma unroll
  for (int i = 0; i < 4; ++i)
#pragma unroll
    for (int j = 0; j < 4; ++j) acc[i][j] = zero;

  for (int kt = 0; kt < nkt; ++kt) {
    __syncthreads();
    const int ko = kt * 32;
    gload16(gaa + ko,            AsB);
    gload16(gaa + 64 * lda + ko, AsB + 4096);
    gload16(gbb + ko,            BsB);
    gload16(gbb + (size_t)64 * 4096 + ko, BsB + 4096);
    __syncthreads();
    bf16x8 af[4], bfv[4];
#pragma unroll
    for (int i = 0; i < 4; ++i) af[i]  = *(const bf16x8*)&As[wr + i * 16 + r16][kg * 8];
#pragma unroll
    for (int j = 0; j < 4; ++j) bfv[j] = *(const bf16x8*)&Bs[wc + j * 16 + r16][kg * 8];
#pragma unroll
    for (int i = 0; i < 4; ++i)
#pragma unroll
      for (int j = 0; j < 4; ++j)
        acc[i][j] = __builtin_amdgcn_mfma_f32_16x16x32_bf16(af[i], bfv[j], acc[i][j], 0, 0, 0);
  }

#pragma unroll
  for (int i = 0; i < 4; ++i)
#pragma unroll
    for (int j = 0; j < 4; ++j) {
      const int col = n0 + wc + j * 16 + r16;
#pragma unroll
      for (int q = 0; q < 4; ++q) {
        const int row = m0 + wr + i * 16 + kg * 4 + q;
        if (init) out[(size_t)row * 512 + col] = acc[i][j][q];
        else      out[(size_t)row * 512 + col] += acc[i][j][q];
      }
    }
}

extern "C" void kernel_launch(void* const* d_in, const int* in_sizes, int n_in,
                              void* d_out, int out_size, void* d_ws, size_t ws_size,
                              hipStream_t stream)
{
  (void)in_sizes; (void)n_in; (void)out_size;
  const float* x  = (const float*)d_in[0];
  const int* mask = (const int*)d_in[1];
  const float* Wq = (const float*)d_in[2];
  const float* Wk = (const float*)d_in[3];
  const float* Wv = (const float*)d_in[4];
  const float* Wp = (const float*)d_in[5];

  const size_t MiB = 1024 * 1024;
  int HC = 1;
  if (ws_size >= 24 * MiB + 32 * 8 * MiB)      HC = 8;
  else if (ws_size >= 24 * MiB + 32 * 4 * MiB) HC = 4;
  else if (ws_size >= 24 * MiB + 32 * 2 * MiB) HC = 2;

  char* ws = (char*)d_ws;
  size_t off = 0;
  u16* xb   = (u16*)(ws + off); off += 8 * MiB;
  u16* wqkv = (u16*)(ws + off); off += 12 * MiB;
  u16* wpb  = (u16*)(ws + off); off += 4 * MiB;
  const size_t qsz = (size_t)4 * HC * 2048 * 512 * 2;
  u16* Qc  = (u16*)(ws + off); off += qsz;
  u16* Kc  = (u16*)(ws + off); off += qsz;
  u16* VTc = (u16*)(ws + off); off += qsz;
  u16* catc = (u16*)(ws + off);

  k_cvt<<<4096, 256, 0, stream>>>(x,  xb, 1048576);
  k_cvt<<<2048, 256, 0, stream>>>(Wq, wqkv,           524288);
  k_cvt<<<2048, 256, 0, stream>>>(Wk, wqkv + 2097152, 524288);
  k_cvt<<<2048, 256, 0, stream>>>(Wv, wqkv + 4194304, 524288);
  k_cvt<<<2048, 256, 0, stream>>>(Wp, wpb,            524288);

  for (int h0 = 0; h0 < 8; h0 += HC) {
    k_gemm_qkv<<<dim3(64, 4, 3 * HC), 256, 0, stream>>>(xb, wqkv, Qc, Kc, VTc, h0, HC);
    k_attn<<<dim3(64, 4 * HC), 256, 0, stream>>>(Qc, Kc, VTc, mask, catc, HC);
    if (HC == 8) {
      // split-K=4: partials into dead Qc (64 MiB), then reduce into d_out
      k_gemm_out_sk<<<dim3(64, 4, 4), 256, 0, stream>>>(catc, wpb, (float*)Qc);
      k_red4<<<4096, 256, 0, stream>>>((const float*)Qc, (float*)d_out, 1048576);
    } else {
      k_gemm_out<<<dim3(64, 4), 256, 0, stream>>>(catc, wpb, (float*)d_out, HC, h0, h0 == 0);
    }
  }
}

// Round 9
// 1255.316 us; speedup vs baseline: 1.1000x; 1.1000x over previous
//
#include <hip/hip_runtime.h>
#include <hip/hip_bf16.h>

// SelfAttention B=4,S=2048,D=512,H=8 — bf16-MFMA, fp32 softmax.
// R8: attn LDS 79->58.5KB (2 blocks/CU target): 64-wide K chunks 2-deep,
//     P overlaid into S_lds (+1 barrier), mask bitmask in LDS,
//     fragment-major V layout (coalesced PV loads).

using bf16x8 = __attribute__((ext_vector_type(8))) short;
using f32x4  = __attribute__((ext_vector_type(4))) float;
typedef unsigned short u16;

__device__ __forceinline__ u16 f2bf(float f) {
  union { float f; unsigned u; } c; c.f = f;
  unsigned r = c.u + 0x7fffu + ((c.u >> 16) & 1u);  // RNE
  return (u16)(r >> 16);
}

__device__ __forceinline__ void gload16(const void* g, void* l) {
  __builtin_amdgcn_global_load_lds((const __attribute__((address_space(1))) unsigned int*)g,
                                   (__attribute__((address_space(3))) unsigned int*)l, 16, 0, 0);
}

__global__ void k_cvt(const float* __restrict__ s, u16* __restrict__ d, int n4) {
  int i = blockIdx.x * 256 + threadIdx.x;
  if (i >= n4) return;
  float4 v = reinterpret_cast<const float4*>(s)[i];
  ushort4 o;
  o.x = f2bf(v.x); o.y = f2bf(v.y); o.z = f2bf(v.z); o.w = f2bf(v.w);
  reinterpret_cast<ushort4*>(d)[i] = o;
}

// ---------------- QKV projection GEMM (NT): out = xb @ W[t*8+h]^T ------------
// K image (t==1): chunk gi=(s>>6)*8+(d>>6) of [64 rows][64 cols], swizzled:
//   idx = bhc<<20 | gi*4096 | (s&63)*64 | ((d&63) ^ ((s&7)<<3))
// V image (t==2): fragment-major for PV:
//   idx = block*512 + ((s>>3)&3)*128 + (e&15)*8 + (s&7),
//   block = (((bhc*32+(s>>6))*4+(e>>7))*2+((s>>5)&1))*8 + ((e>>4)&7).
__global__ __launch_bounds__(256) void k_gemm_qkv(
    const u16* __restrict__ xb, const u16* __restrict__ w,
    u16* __restrict__ Qc, u16* __restrict__ Kc, u16* __restrict__ VF,
    int h0, int HC)
{
  __shared__ u16 As[128][32];
  __shared__ u16 Bs[128][32];

  const int m0 = blockIdx.x * 128;
  const int n0 = blockIdx.y * 128;
  const int zz = blockIdx.z;
  const int t  = zz / HC, hr = zz % HC;
  const int h  = h0 + hr;

  const int tid  = threadIdx.x;
  const int lane = tid & 63, wv = tid >> 6;
  const int wr = (wv >> 1) * 64, wc = (wv & 1) * 64;
  const int r16 = lane & 15, kg = lane >> 4;

  const u16* wbase = w + (size_t)(t * 8 + h) * 512 * 512;
  const int strow = tid >> 2;
  const int sc4   = (tid & 3) * 8;

  const u16* gaa = xb    + (size_t)(m0 + strow) * 512 + sc4;
  const u16* gbb = wbase + (size_t)(n0 + strow) * 512 + sc4;
  char* AsB = (char*)&As[0][0] + wv * 1024;
  char* BsB = (char*)&Bs[0][0] + wv * 1024;

  f32x4 acc[4][4];
  f32x4 zero = {0.f, 0.f, 0.f, 0.f};
#pragma unroll
  for (int i = 0; i < 4; ++i)
#pragma unroll
    for (int j = 0; j < 4; ++j) acc[i][j] = zero;

  for (int kt = 0; kt < 16; ++kt) {
    __syncthreads();
    const int ko = kt * 32;
    gload16(gaa + ko,            AsB);
    gload16(gaa + 64 * 512 + ko, AsB + 4096);
    gload16(gbb + ko,            BsB);
    gload16(gbb + 64 * 512 + ko, BsB + 4096);
    __syncthreads();
    bf16x8 af[4], bfv[4];
#pragma unroll
    for (int i = 0; i < 4; ++i) af[i]  = *(const bf16x8*)&As[wr + i * 16 + r16][kg * 8];
#pragma unroll
    for (int j = 0; j < 4; ++j) bfv[j] = *(const bf16x8*)&Bs[wc + j * 16 + r16][kg * 8];
#pragma unroll
    for (int i = 0; i < 4; ++i)
#pragma unroll
      for (int j = 0; j < 4; ++j)
        acc[i][j] = __builtin_amdgcn_mfma_f32_16x16x32_bf16(af[i], bfv[j], acc[i][j], 0, 0, 0);
  }

  // C lane map: row=(lane>>4)*4+reg, col=lane&15
#pragma unroll
  for (int i = 0; i < 4; ++i) {
    const int mbase = m0 + wr + i * 16 + kg * 4;
    const int b   = mbase >> 11;
    const int sl  = mbase & 2047;
    const int bhc = b * HC + hr;
#pragma unroll
    for (int j = 0; j < 4; ++j) {
      const int col = n0 + wc + j * 16 + r16;
      if (t == 2) {        // V fragment-major
        const size_t base =
            ((((size_t)(bhc * 32 + (sl >> 6)) * 4 + (col >> 7)) * 2 + ((sl >> 5) & 1)) * 8
             + ((col >> 4) & 7)) * 64;
        const size_t idx = (base + ((sl >> 3) & 3) * 16 + (col & 15)) * 8 + (sl & 7);
        ushort4 o;
        o.x = f2bf(acc[i][j][0]); o.y = f2bf(acc[i][j][1]);
        o.z = f2bf(acc[i][j][2]); o.w = f2bf(acc[i][j][3]);
        *(ushort4*)&VF[idx] = o;
      } else if (t == 1) { // K: swizzled 64-wide chunk image
#pragma unroll
        for (int q = 0; q < 4; ++q) {
          const int s = sl + q;
          const size_t idx = ((size_t)bhc << 20)
                           + (size_t)((s >> 6) * 8 + (col >> 6)) * 4096
                           + (s & 63) * 64 + ((col & 63) ^ ((s & 7) << 3));
          Kc[idx] = f2bf(acc[i][j][q]);
        }
      } else {             // Q: plain row-major [bhc][s][e]
#pragma unroll
        for (int q = 0; q < 4; ++q)
          Qc[((size_t)bhc * 2048 + sl + q) * 512 + col] = f2bf(acc[i][j][q]);
      }
    }
  }
}

// ---------------- flash attention v5 ----------------
// 4 waves, QBLK=32, KVBLK=64, 64-wide d-chunks 2-deep (counted vmcnt(2)),
// wave-private K rows, P overlaid in S_lds, mask bitmask in LDS, 3 barriers/it.
__global__ __launch_bounds__(256) void k_attn(
    const u16* __restrict__ Qc, const u16* __restrict__ Kc, const u16* __restrict__ VF,
    const int* __restrict__ mask, u16* __restrict__ catc, int HC)
{
  __shared__ u16  Qs[32 * 512];              // XOR-swizzled rows (32 KB)
  __shared__ u16  Ks[2 * 4096];              // 2 chunk buffers [64][64] swizzled (16 KB)
  __shared__ float S_lds[32][68];            // S fp32; P bf16 overlaid in low 16B of each 32B chunk
  __shared__ unsigned long long Mb[32];      // mask bits, col c -> Mb[c>>6] bit (c&63)
  __shared__ float m_run[32], l_run[32], alpha_s[32];

  const int lin = blockIdx.x + (blockIdx.y << 6);
  int qt, bhc;
  if (HC >= 2) {           // bh-clustered XCD mapping
    const int pxb  = HC >> 1;
    const int slot = lin >> 3;
    bhc = (lin & 7) * pxb + (slot >> 6);
    qt  = slot & 63;
  } else {
    qt = lin & 63; bhc = lin >> 6;
  }

  const int b = bhc / HC, hr = bhc % HC;
  const int q0 = qt * 32;

  const int tid = threadIdx.x, lane = tid & 63, wv = tid >> 6;
  const int r16 = lane & 15, kg = lane >> 4;

  const u16* Qg = Qc + ((size_t)bhc * 2048 + q0) * 512;
  const u16* Kg = Kc + ((size_t)bhc << 20);
  const u16* Vg = VF + ((size_t)bhc << 20);
  const int* mrow = mask + b * 2048;

  // stage Q swizzled
  for (int s = tid; s < 2048; s += 256) {
    const int row = s >> 6, col = (s & 63) * 8;
    *(int4*)&Qs[row * 512 + (col ^ ((row & 7) << 3))] =
        *(const int4*)(Qg + row * 512 + col);
  }
  // stage mask bits (per-wave ballot over 64 cols)
#pragma unroll
  for (int r = 0; r < 8; ++r) {
    const int c = r * 256 + wv * 64 + lane;
    unsigned long long bm = __ballot(mrow[c] != 0);
    if (lane == 0) Mb[r * 4 + wv] = bm;
  }
  if (tid < 32) { m_run[tid] = -__builtin_inff(); l_run[tid] = 0.f; }

  // K chunk issue: wave wv loads its rows 16wv..16wv+15 (64 cols = 2KB = 2 gloads)
  auto kissue = [&](int gi, int cur) {
    const u16* g = Kg + (size_t)gi * 4096 + wv * 1024 + lane * 8;
    u16* l = &Ks[cur * 4096 + wv * 1024];
    gload16(g, l);
    gload16(g + 512, l + 512);
  };

  kissue(0, 0);
  kissue(1, 1);

  asm volatile("s_waitcnt lgkmcnt(0)" ::: "memory");
  __builtin_amdgcn_s_barrier();    // Q + mask visible; K gloads in flight

  const int sm_row = tid >> 3, sm_c0 = (tid & 7) * 8;
  const int rm = mrow[q0 + sm_row];
  const int krow = wv * 16 + r16;
  const int kswz = (krow & 7) << 3;

  f32x4 acc[2][8];
  f32x4 zero = {0.f, 0.f, 0.f, 0.f};
#pragma unroll
  for (int mi = 0; mi < 2; ++mi)
#pragma unroll
    for (int nf = 0; nf < 8; ++nf) acc[mi][nf] = zero;

  const float scale = 0.044194173824159216f;  // 1/sqrt(512)

  for (int it = 0; it < 32; ++it) {
    f32x4 sacc[2] = {zero, zero};

    // ---- QK^T over 8 d-chunks (64-wide); rolling 2-deep K pipeline ----
#pragma unroll
    for (int c = 0; c < 8; ++c) {
      const int gi = it * 8 + c;
      const int cur = gi & 1;
      asm volatile("s_waitcnt vmcnt(2)" ::: "memory");  // chunk gi landed
      __builtin_amdgcn_s_setprio(1);
#pragma unroll
      for (int ks = 0; ks < 2; ++ks) {
        bf16x8 kb = *(const bf16x8*)&Ks[cur * 4096 + krow * 64 + ((ks * 32 + kg * 8) ^ kswz)];
#pragma unroll
        for (int mi = 0; mi < 2; ++mi) {
          const int qrow = mi * 16 + r16;
          bf16x8 qa = *(const bf16x8*)&Qs[qrow * 512 +
              ((c * 64 + ks * 32 + kg * 8) ^ ((qrow & 7) << 3))];
          sacc[mi] = __builtin_amdgcn_mfma_f32_16x16x32_bf16(qa, kb, sacc[mi], 0, 0, 0);
        }
      }
      __builtin_amdgcn_s_setprio(0);
      if (c == 7) {  // publish raw S strip
#pragma unroll
        for (int mi = 0; mi < 2; ++mi)
#pragma unroll
          for (int q = 0; q < 4; ++q)
            S_lds[mi * 16 + kg * 4 + q][wv * 16 + r16] = sacc[mi][q];
      }
      asm volatile("s_waitcnt lgkmcnt(0)" ::: "memory");
      __builtin_amdgcn_sched_barrier(0);
      if (gi + 2 < 256) kissue(gi + 2, cur);            // wave-private rows
    }
    __builtin_amdgcn_s_barrier();    // S visible; K loads in flight

    // ---- V fragment preload (fragment-major: lane-contiguous 1KB blocks) ----
    bf16x8 vfrag[2][8];
#pragma unroll
    for (int ks = 0; ks < 2; ++ks)
#pragma unroll
      for (int nf = 0; nf < 8; ++nf)
        vfrag[ks][nf] = *(const bf16x8*)(Vg +
            ((((size_t)it * 4 + wv) * 2 + ks) * 8 + nf) * 512 + (size_t)lane * 8);

    // ---- online softmax (32 rows x 64 cols, 8 threads/row) ----
    {
      float4 sA = *(float4*)&S_lds[sm_row][sm_c0];
      float4 sB = *(float4*)&S_lds[sm_row][sm_c0 + 4];
      const unsigned byte = rm ? (unsigned)((Mb[it] >> sm_c0) & 0xFF) : 0u;
      float s0 = (byte & 1)   ? sA.x * scale : -1e9f;
      float s1 = (byte & 2)   ? sA.y * scale : -1e9f;
      float s2 = (byte & 4)   ? sA.z * scale : -1e9f;
      float s3 = (byte & 8)   ? sA.w * scale : -1e9f;
      float s4 = (byte & 16)  ? sB.x * scale : -1e9f;
      float s5 = (byte & 32)  ? sB.y * scale : -1e9f;
      float s6 = (byte & 64)  ? sB.z * scale : -1e9f;
      float s7 = (byte & 128) ? sB.w * scale : -1e9f;
      float mt = fmaxf(fmaxf(fmaxf(s0, s1), fmaxf(s2, s3)),
                       fmaxf(fmaxf(s4, s5), fmaxf(s6, s7)));
      mt = fmaxf(mt, __shfl_xor(mt, 1));
      mt = fmaxf(mt, __shfl_xor(mt, 2));
      mt = fmaxf(mt, __shfl_xor(mt, 4));
      const float mo = m_run[sm_row];
      const float mn = fmaxf(mo, mt);
      const float al = __expf(mo - mn);
      float p0 = __expf(s0 - mn), p1 = __expf(s1 - mn);
      float p2 = __expf(s2 - mn), p3 = __expf(s3 - mn);
      float p4 = __expf(s4 - mn), p5 = __expf(s5 - mn);
      float p6 = __expf(s6 - mn), p7 = __expf(s7 - mn);
      float ps = ((p0 + p1) + (p2 + p3)) + ((p4 + p5) + (p6 + p7));
      ps += __shfl_xor(ps, 1); ps += __shfl_xor(ps, 2); ps += __shfl_xor(ps, 4);
      ushort4 w0, w1;
      w0.x = f2bf(p0); w0.y = f2bf(p1); w0.z = f2bf(p2); w0.w = f2bf(p3);
      w1.x = f2bf(p4); w1.y = f2bf(p5); w1.z = f2bf(p6); w1.w = f2bf(p7);
      u16* Pcell = (u16*)&S_lds[sm_row][sm_c0];   // overlay: own 16B in own 32B
      *(ushort4*)(Pcell)     = w0;
      *(ushort4*)(Pcell + 4) = w1;
      if ((tid & 7) == 0) {
        m_run[sm_row] = mn;
        l_run[sm_row] = l_run[sm_row] * al + ps;
        alpha_s[sm_row] = al;
      }
    }
    asm volatile("s_waitcnt lgkmcnt(0)" ::: "memory");
    __builtin_amdgcn_s_barrier();    // P/alpha visible

    // ---- rescale + PV ----
    float alq[2][4];
#pragma unroll
    for (int mi = 0; mi < 2; ++mi)
#pragma unroll
      for (int q = 0; q < 4; ++q) alq[mi][q] = alpha_s[mi * 16 + kg * 4 + q];
#pragma unroll
    for (int mi = 0; mi < 2; ++mi)
#pragma unroll
      for (int nf = 0; nf < 8; ++nf) {
        acc[mi][nf][0] *= alq[mi][0]; acc[mi][nf][1] *= alq[mi][1];
        acc[mi][nf][2] *= alq[mi][2]; acc[mi][nf][3] *= alq[mi][3];
      }
    __builtin_amdgcn_s_setprio(1);
#pragma unroll
    for (int ks = 0; ks < 2; ++ks) {
      bf16x8 pa0 = *(const bf16x8*)((const u16*)&S_lds[r16][0]      + (ks * 32 + kg * 8) * 2);
      bf16x8 pa1 = *(const bf16x8*)((const u16*)&S_lds[16 + r16][0] + (ks * 32 + kg * 8) * 2);
#pragma unroll
      for (int nf = 0; nf < 8; ++nf) {
        acc[0][nf] = __builtin_amdgcn_mfma_f32_16x16x32_bf16(pa0, vfrag[ks][nf], acc[0][nf], 0, 0, 0);
        acc[1][nf] = __builtin_amdgcn_mfma_f32_16x16x32_bf16(pa1, vfrag[ks][nf], acc[1][nf], 0, 0, 0);
      }
    }
    __builtin_amdgcn_s_setprio(0);
    asm volatile("s_waitcnt lgkmcnt(0)" ::: "memory");
    __builtin_amdgcn_s_barrier();    // protect P overlay from next S publish
  }

  // ---- epilogue ----
  float rinv[2][4];
#pragma unroll
  for (int mi = 0; mi < 2; ++mi)
#pragma unroll
    for (int q = 0; q < 4; ++q) rinv[mi][q] = 1.0f / l_run[mi * 16 + kg * 4 + q];
  const int ldc = HC * 512;
#pragma unroll
  for (int mi = 0; mi < 2; ++mi)
#pragma unroll
    for (int nf = 0; nf < 8; ++nf) {
      const int col = hr * 512 + wv * 128 + nf * 16 + r16;
#pragma unroll
      for (int q = 0; q < 4; ++q) {
        const int row = b * 2048 + q0 + mi * 16 + kg * 4 + q;
        catc[(size_t)row * ldc + col] = f2bf(acc[mi][nf][q] * rinv[mi][q]);
      }
    }
}

// ------------- output projection, split-K=4 (HC=8): partial[z] = cat_z @ Wp_z^T
__global__ __launch_bounds__(256) void k_gemm_out_sk(
    const u16* __restrict__ A, const u16* __restrict__ Bw, float* __restrict__ partial)
{
  __shared__ u16 As[128][32];
  __shared__ u16 Bs[128][32];

  const int m0 = blockIdx.x * 128;
  const int n0 = blockIdx.y * 128;
  const int z  = blockIdx.z;
  const int tid = threadIdx.x, lane = tid & 63, wv = tid >> 6;
  const int wr = (wv >> 1) * 64, wc = (wv & 1) * 64;
  const int r16 = lane & 15, kg = lane >> 4;
  const int strow = tid >> 2, sc4 = (tid & 3) * 8;

  const u16* gaa = A  + (size_t)(m0 + strow) * 4096 + z * 1024 + sc4;
  const u16* gbb = Bw + (size_t)(n0 + strow) * 4096 + z * 1024 + sc4;
  char* AsB = (char*)&As[0][0] + wv * 1024;
  char* BsB = (char*)&Bs[0][0] + wv * 1024;

  f32x4 acc[4][4];
  f32x4 zero = {0.f, 0.f, 0.f, 0.f};
#pragma unroll
  for (int i = 0; i < 4; ++i)
#pragma unroll
    for (int j = 0; j < 4; ++j) acc[i][j] = zero;

  for (int kt = 0; kt < 32; ++kt) {
    __syncthreads();
    const int ko = kt * 32;
    gload16(gaa + ko,                     AsB);
    gload16(gaa + (size_t)64 * 4096 + ko, AsB + 4096);
    gload16(gbb + ko,                     BsB);
    gload16(gbb + (size_t)64 * 4096 + ko, BsB + 4096);
    __syncthreads();
    bf16x8 af[4], bfv[4];
#pragma unroll
    for (int i = 0; i < 4; ++i) af[i]  = *(const bf16x8*)&As[wr + i * 16 + r16][kg * 8];
#pragma unroll
    for (int j = 0; j < 4; ++j) bfv[j] = *(const bf16x8*)&Bs[wc + j * 16 + r16][kg * 8];
#pragma unroll
    for (int i = 0; i < 4; ++i)
#pragma unroll
      for (int j = 0; j < 4; ++j)
        acc[i][j] = __builtin_amdgcn_mfma_f32_16x16x32_bf16(af[i], bfv[j], acc[i][j], 0, 0, 0);
  }

  float* dst = partial + (size_t)z * 4194304;
#pragma unroll
  for (int i = 0; i < 4; ++i)
#pragma unroll
    for (int j = 0; j < 4; ++j) {
      const int col = n0 + wc + j * 16 + r16;
#pragma unroll
      for (int q = 0; q < 4; ++q) {
        const int row = m0 + wr + i * 16 + kg * 4 + q;
        dst[(size_t)row * 512 + col] = acc[i][j][q];
      }
    }
}

__global__ void k_red4(const float* __restrict__ p, float* __restrict__ out, int n4) {
  int i = blockIdx.x * 256 + threadIdx.x;
  if (i >= n4) return;
  float4 a = reinterpret_cast<const float4*>(p)[i];
  float4 b = reinterpret_cast<const float4*>(p + 4194304)[i];
  float4 c = reinterpret_cast<const float4*>(p + 8388608)[i];
  float4 d = reinterpret_cast<const float4*>(p + 12582912)[i];
  float4 o;
  o.x = (a.x + b.x) + (c.x + d.x);
  o.y = (a.y + b.y) + (c.y + d.y);
  o.z = (a.z + b.z) + (c.z + d.z);
  o.w = (a.w + b.w) + (c.w + d.w);
  reinterpret_cast<float4*>(out)[i] = o;
}

// ------------- output projection GEMM (NT, accumulating) — HC<8 fallback
__global__ __launch_bounds__(256) void k_gemm_out(
    const u16* __restrict__ A, const u16* __restrict__ Bw, float* __restrict__ out,
    int HC, int h0, int init)
{
  __shared__ u16 As[128][32];
  __shared__ u16 Bs[128][32];

  const int m0 = blockIdx.x * 128;
  const int n0 = blockIdx.y * 128;
  const int tid = threadIdx.x, lane = tid & 63, wv = tid >> 6;
  const int wr = (wv >> 1) * 64, wc = (wv & 1) * 64;
  const int r16 = lane & 15, kg = lane >> 4;
  const int strow = tid >> 2, sc4 = (tid & 3) * 8;
  const size_t lda = (size_t)HC * 512;
  const int nkt = HC * 16;

  const u16* gaa = A  + (size_t)(m0 + strow) * lda + sc4;
  const u16* gbb = Bw + (size_t)(n0 + strow) * 4096 + h0 * 512 + sc4;
  char* AsB = (char*)&As[0][0] + wv * 1024;
  char* BsB = (char*)&Bs[0][0] + wv * 1024;

  f32x4 acc[4][4];
  f32x4 zero = {0.f, 0.f, 0.f, 0.f};
#pragma unroll
  for (int i = 0; i < 4; ++i)
#pragma unroll
    for (int j = 0; j < 4; ++j) acc[i][j] = zero;

  for (int kt = 0; kt < nkt; ++kt) {
    __syncthreads();
    const int ko = kt * 32;
    gload16(gaa + ko,            AsB);
    gload16(gaa + 64 * lda + ko, AsB + 4096);
    gload16(gbb + ko,            BsB);
    gload16(gbb + (size_t)64 * 4096 + ko, BsB + 4096);
    __syncthreads();
    bf16x8 af[4], bfv[4];
#pragma unroll
    for (int i = 0; i < 4; ++i) af[i]  = *(const bf16x8*)&As[wr + i * 16 + r16][kg * 8];
#pragma unroll
    for (int j = 0; j < 4; ++j) bfv[j] = *(const bf16x8*)&Bs[wc + j * 16 + r16][kg * 8];
#pragma unroll
    for (int i = 0; i < 4; ++i)
#pragma unroll
      for (int j = 0; j < 4; ++j)
        acc[i][j] = __builtin_amdgcn_mfma_f32_16x16x32_bf16(af[i], bfv[j], acc[i][j], 0, 0, 0);
  }

#pragma unroll
  for (int i = 0; i < 4; ++i)
#pragma unroll
    for (int j = 0; j < 4; ++j) {
      const int col = n0 + wc + j * 16 + r16;
#pragma unroll
      for (int q = 0; q < 4; ++q) {
        const int row = m0 + wr + i * 16 + kg * 4 + q;
        if (init) out[(size_t)row * 512 + col] = acc[i][j][q];
        else      out[(size_t)row * 512 + col] += acc[i][j][q];
      }
    }
}

extern "C" void kernel_launch(void* const* d_in, const int* in_sizes, int n_in,
                              void* d_out, int out_size, void* d_ws, size_t ws_size,
                              hipStream_t stream)
{
  (void)in_sizes; (void)n_in; (void)out_size;
  const float* x  = (const float*)d_in[0];
  const int* mask = (const int*)d_in[1];
  const float* Wq = (const float*)d_in[2];
  const float* Wk = (const float*)d_in[3];
  const float* Wv = (const float*)d_in[4];
  const float* Wp = (const float*)d_in[5];

  const size_t MiB = 1024 * 1024;
  int HC = 1;
  if (ws_size >= 24 * MiB + 32 * 8 * MiB)      HC = 8;
  else if (ws_size >= 24 * MiB + 32 * 4 * MiB) HC = 4;
  else if (ws_size >= 24 * MiB + 32 * 2 * MiB) HC = 2;

  char* ws = (char*)d_ws;
  size_t off = 0;
  u16* xb   = (u16*)(ws + off); off += 8 * MiB;
  u16* wqkv = (u16*)(ws + off); off += 12 * MiB;
  u16* wpb  = (u16*)(ws + off); off += 4 * MiB;
  const size_t qsz = (size_t)4 * HC * 2048 * 512 * 2;
  u16* Qc  = (u16*)(ws + off); off += qsz;
  u16* Kc  = (u16*)(ws + off); off += qsz;
  u16* VF  = (u16*)(ws + off); off += qsz;
  u16* catc = (u16*)(ws + off);

  k_cvt<<<4096, 256, 0, stream>>>(x,  xb, 1048576);
  k_cvt<<<2048, 256, 0, stream>>>(Wq, wqkv,           524288);
  k_cvt<<<2048, 256, 0, stream>>>(Wk, wqkv + 2097152, 524288);
  k_cvt<<<2048, 256, 0, stream>>>(Wv, wqkv + 4194304, 524288);
  k_cvt<<<2048, 256, 0, stream>>>(Wp, wpb,            524288);

  for (int h0 = 0; h0 < 8; h0 += HC) {
    k_gemm_qkv<<<dim3(64, 4, 3 * HC), 256, 0, stream>>>(xb, wqkv, Qc, Kc, VF, h0, HC);
    k_attn<<<dim3(64, 4 * HC), 256, 0, stream>>>(Qc, Kc, VF, mask, catc, HC);
    if (HC == 8) {
      k_gemm_out_sk<<<dim3(64, 4, 4), 256, 0, stream>>>(catc, wpb, (float*)Qc);
      k_red4<<<4096, 256, 0, stream>>>((const float*)Qc, (float*)d_out, 1048576);
    } else {
      k_gemm_out<<<dim3(64, 4), 256, 0, stream>>>(catc, wpb, (float*)d_out, HC, h0, h0 == 0);
    }
  }
}